// Round 1
// baseline (436.570 us; speedup 1.0000x reference)
//
#include <hip/hip_runtime.h>

// SST input layer: window partition + per-window drop + flat2win re-indexing.
// Static config from the reference:
//   WIN=12, GRID=468, BATCH=4, SHIFTS=((0,0),(6,6)), MAX_WIN_Y=40,
//   MAX_WIN_PER_SAMPLE=1600 -> window ids in [0, 6400)
//   DROP_INFO: cnt<30 -> lvl0,target30 ; cnt<60 -> lvl1,target60 ;
//              cnt<100000 -> lvl2,target100 ; else lvl-1,target0

#define NWIN 6400
#define SEG_CAP 3072   // per-window LDS segment cap (12 KB); stat max count ~100

// ---- K0: zero the atomic counters (cnt0,cur0,cnt1,cur1 contiguous) + keepF ----
__global__ void k_zero(int* __restrict__ hdr, int* __restrict__ keepF, int n) {
    int i = blockIdx.x * blockDim.x + threadIdx.x;
    if (i < 4 * NWIN) hdr[i] = 0;
    if (i < n) keepF[i] = 0;
}

// ---- K1: per-voxel window ids for both shifts + histogram of shift-0 windows ----
__global__ void k_windows(const int* __restrict__ coors, int n,
                          int* __restrict__ w0a, int* __restrict__ w1a,
                          int* __restrict__ cnt0) {
    int i = blockIdx.x * blockDim.x + threadIdx.x;
    if (i >= n) return;
    int b = coors[4 * i];
    int y = coors[4 * i + 2];
    int x = coors[4 * i + 3];
    int w0 = b * 1600 + (x / 12) * 40 + (y / 12);
    int w1 = b * 1600 + ((x + 6) / 12) * 40 + ((y + 6) / 12);
    w0a[i] = w0;
    w1a[i] = w1;
    atomicAdd(&cnt0[w0], 1);
}

// ---- K2: exclusive prefix over 6400 window counts + per-window drop level ----
__global__ void k_scan(const int* __restrict__ cnt, int* __restrict__ base,
                       int* __restrict__ lvlW) {
    __shared__ int psum[256];
    int t = threadIdx.x;
    int st = t * 25;           // 256 * 25 = 6400
    int s = 0;
    for (int j = 0; j < 25; j++) s += cnt[st + j];
    psum[t] = s;
    __syncthreads();
    if (t == 0) {
        int acc = 0;
        for (int j = 0; j < 256; j++) { int v = psum[j]; psum[j] = acc; acc += v; }
    }
    __syncthreads();
    int acc = psum[t];
    for (int j = 0; j < 25; j++) {
        int w = st + j;
        int c = cnt[w];
        base[w] = acc;
        acc += c;
        int lvl;
        if (c < 30) lvl = 0;
        else if (c < 60) lvl = 1;
        else if (c < 100000) lvl = 2;
        else lvl = -1;
        lvlW[w] = lvl;
    }
}

// ---- masked histogram (shift-1 counts among keep0 survivors) ----
__global__ void k_count_masked(const int* __restrict__ wa, const int* __restrict__ mask,
                               int n, int* __restrict__ cnt) {
    int i = blockIdx.x * blockDim.x + threadIdx.x;
    if (i >= n) return;
    if (!mask[i]) return;
    atomicAdd(&cnt[wa[i]], 1);
}

// ---- scatter voxel indices into per-window segments (arbitrary order) ----
__global__ void k_scatter(const int* __restrict__ wa, const int* __restrict__ mask, int n,
                          const int* __restrict__ base, int* __restrict__ cur,
                          int* __restrict__ seg) {
    int i = blockIdx.x * blockDim.x + threadIdx.x;
    if (i >= n) return;
    if (mask && !mask[i]) return;
    int w = wa[i];
    int p = atomicAdd(&cur[w], 1);
    seg[base[w] + p] = i;
}

// ---- per-window: rank by original index (stable-sort inner) -> keep flag ----
__global__ void k_rankkeep(const int* __restrict__ cnt, const int* __restrict__ base,
                           const int* __restrict__ seg, int* __restrict__ keepOut) {
    int w = blockIdx.x;
    int k = cnt[w];
    if (k == 0) return;
    int bs = base[w];
    int target;
    if (k < 30) target = 30;
    else if (k < 60) target = 60;
    else if (k < 100000) target = 100;
    else target = 0;
    __shared__ int lds[SEG_CAP];
    if (k <= SEG_CAP) {
        for (int j = threadIdx.x; j < k; j += blockDim.x) lds[j] = seg[bs + j];
        __syncthreads();
        for (int e = threadIdx.x; e < k; e += blockDim.x) {
            int v = lds[e];
            int r = 0;
            for (int j = 0; j < k; j++) r += (lds[j] < v) ? 1 : 0;
            keepOut[v] = (r < target) ? 1 : 0;
        }
    } else {  // statistical never; correctness fallback
        for (int e = threadIdx.x; e < k; e += blockDim.x) {
            int v = seg[bs + e];
            int r = 0;
            for (int j = 0; j < k; j++) r += (seg[bs + j] < v) ? 1 : 0;
            keepOut[v] = (r < target) ? 1 : 0;
        }
    }
}

// ---- per-window: rank among FINAL-kept members + kept count (for flat2win) ----
__global__ void k_rankkept(const int* __restrict__ cnt, const int* __restrict__ base,
                           const int* __restrict__ seg, const int* __restrict__ keepF,
                           int* __restrict__ rk, int* __restrict__ keptC) {
    int w = blockIdx.x;
    int k = cnt[w];
    __shared__ int lds[SEG_CAP];
    __shared__ int red[64];
    int local = 0;
    if (k > 0) {
        int bs = base[w];
        if (k <= SEG_CAP) {
            for (int j = threadIdx.x; j < k; j += blockDim.x) {
                int v = seg[bs + j];
                lds[j] = v | (keepF[v] << 30);   // pack kept flag in bit 30 (idx < 2^30)
            }
            __syncthreads();
            for (int e = threadIdx.x; e < k; e += blockDim.x) {
                int enc = lds[e];
                int kept = enc >> 30;
                local += kept;
                if (!kept) continue;
                int v = enc & 0x3FFFFFFF;
                int r = 0;
                for (int j = 0; j < k; j++) {
                    int ej = lds[j];
                    r += (ej >> 30) & (int)((ej & 0x3FFFFFFF) < v);
                }
                rk[v] = r;
            }
        } else {
            for (int e = threadIdx.x; e < k; e += blockDim.x) {
                int v = seg[bs + e];
                int f = keepF[v];
                local += f;
                if (!f) continue;
                int r = 0;
                for (int j = 0; j < k; j++) {
                    int u = seg[bs + j];
                    r += (keepF[u] && (u < v)) ? 1 : 0;
                }
                rk[v] = r;
            }
        }
    }
    red[threadIdx.x] = local;
    __syncthreads();
    if (threadIdx.x == 0) {
        int s = 0;
        for (int j = 0; j < 64; j++) s += red[j];
        keptC[w] = s;
    }
}

// ---- dense rank of windows per drop level (make_continuous_inds) ----
__global__ void k_conti(const int* __restrict__ lvlW, const int* __restrict__ keptC,
                        int* __restrict__ conti) {
    __shared__ int pc0[256], pc1[256], pc2[256];
    int t = threadIdx.x;
    int st = t * 25;
    int c0 = 0, c1 = 0, c2 = 0;
    for (int j = 0; j < 25; j++) {
        int w = st + j;
        if (keptC[w] > 0) {
            int l = lvlW[w];
            c0 += (l == 0); c1 += (l == 1); c2 += (l == 2);
        }
    }
    pc0[t] = c0; pc1[t] = c1; pc2[t] = c2;
    __syncthreads();
    if (t == 0) {
        int a = 0, b = 0, c = 0;
        for (int j = 0; j < 256; j++) {
            int v0 = pc0[j], v1 = pc1[j], v2 = pc2[j];
            pc0[j] = a; pc1[j] = b; pc2[j] = c;
            a += v0; b += v1; c += v2;
        }
    }
    __syncthreads();
    int a0 = pc0[t], a1 = pc1[t], a2 = pc2[t];
    for (int j = 0; j < 25; j++) {
        int w = st + j;
        int l = lvlW[w];
        int cc = (l == 0) ? a0 : (l == 1) ? a1 : (l == 2) ? a2 : 0;
        conti[w] = cc;
        if (keptC[w] > 0) {
            if (l == 0) a0++; else if (l == 1) a1++; else if (l == 2) a2++;
        }
    }
}

// ---- per-voxel scalar outputs (7 arrays, written as float32) ----
__global__ void k_final(int n, const int* __restrict__ w0a, const int* __restrict__ w1a,
                        const int* __restrict__ keep0, const int* __restrict__ keepF,
                        const int* __restrict__ lvlW0, const int* __restrict__ lvlW1,
                        const int* __restrict__ conti0, const int* __restrict__ conti1,
                        const int* __restrict__ rk0, const int* __restrict__ rk1,
                        float* __restrict__ out) {
    int i = blockIdx.x * blockDim.x + threadIdx.x;
    if (i >= n) return;
    size_t N = (size_t)n;
    float* o = out + N * 128;   // after feat block
    int w0 = w0a[i], w1 = w1a[i];
    int k0 = keep0[i];
    int kf = keepF[i];
    int l0 = lvlW0[w0];
    int l1 = k0 ? lvlW1[w1] : -1;
    int f0 = -1, f1 = -1;
    if (kf) {
        int mt0 = (l0 == 0) ? 30 : (l0 == 1) ? 60 : 100;
        int mt1 = (l1 == 0) ? 30 : (l1 == 1) ? 60 : 100;
        f0 = conti0[w0] * mt0 + rk0[i];
        f1 = conti1[w1] * mt1 + rk1[i];
    }
    o[i]         = (float)kf;   // keep
    o[N + i]     = (float)l0;   // lvl0
    o[2 * N + i] = (float)l1;   // lvl1
    o[3 * N + i] = (float)w0;   // bwi0
    o[4 * N + i] = (float)w1;   // bwi1
    o[5 * N + i] = (float)f0;   // f2w0
    o[6 * N + i] = (float)f1;   // f2w1
}

// ---- masked feature copy (the HBM-bound part): float4-vectorized ----
__global__ void k_feat(const float4* __restrict__ in, const int* __restrict__ keepF,
                       float4* __restrict__ out, int n) {
    int gid = blockIdx.x * blockDim.x + threadIdx.x;
    int total = n * 32;            // 128 floats = 32 float4 per row
    if (gid >= total) return;
    int row = gid >> 5;
    float4 v = in[gid];
    if (!keepF[row]) { v.x = 0.f; v.y = 0.f; v.z = 0.f; v.w = 0.f; }
    out[gid] = v;
}

extern "C" void kernel_launch(void* const* d_in, const int* in_sizes, int n_in,
                              void* d_out, int out_size, void* d_ws, size_t ws_size,
                              hipStream_t stream) {
    (void)n_in; (void)out_size; (void)ws_size;
    const float* feat = (const float*)d_in[0];
    const int* coors  = (const int*)d_in[1];
    int n = in_sizes[1] / 4;           // coors is [N,4]
    float* out = (float*)d_out;
    int* ws = (int*)d_ws;

    // workspace layout (ints). Header counters contiguous for one-shot zeroing.
    int* cnt0   = ws;                  // 6400  (zeroed)
    // cur0 = ws+6400, cnt1 = ws+12800, cur1 = ws+19200 (all zeroed with cnt0)
    int* cur0   = ws + 6400;
    int* cnt1   = ws + 12800;
    int* cur1   = ws + 19200;
    int* base0  = ws + 25600;
    int* base1  = ws + 32000;
    int* lvlW0  = ws + 38400;
    int* lvlW1  = ws + 44800;
    int* keptC0 = ws + 51200;
    int* keptC1 = ws + 57600;
    int* conti0 = ws + 64000;
    int* conti1 = ws + 70400;
    int* w0a    = ws + 76800;          // N each from here
    int* w1a    = w0a + n;
    int* seg0   = w1a + n;
    int* seg1   = seg0 + n;
    int* keep0  = seg1 + n;
    int* keepF  = keep0 + n;
    int* rk0    = keepF + n;
    int* rk1    = rk0 + n;
    // total ws use: (76800 + 8*N) * 4 bytes  (~9.9 MB at N=300000)

    int nb = (n + 255) / 256;
    int zmax = (n > 4 * NWIN) ? n : 4 * NWIN;
    int zb = (zmax + 255) / 256;

    k_zero<<<zb, 256, 0, stream>>>(cnt0, keepF, n);
    k_windows<<<nb, 256, 0, stream>>>(coors, n, w0a, w1a, cnt0);
    k_scan<<<1, 256, 0, stream>>>(cnt0, base0, lvlW0);
    k_scatter<<<nb, 256, 0, stream>>>(w0a, (const int*)nullptr, n, base0, cur0, seg0);
    k_rankkeep<<<NWIN, 64, 0, stream>>>(cnt0, base0, seg0, keep0);
    k_count_masked<<<nb, 256, 0, stream>>>(w1a, keep0, n, cnt1);
    k_scan<<<1, 256, 0, stream>>>(cnt1, base1, lvlW1);
    k_scatter<<<nb, 256, 0, stream>>>(w1a, keep0, n, base1, cur1, seg1);
    k_rankkeep<<<NWIN, 64, 0, stream>>>(cnt1, base1, seg1, keepF);
    k_rankkept<<<NWIN, 64, 0, stream>>>(cnt0, base0, seg0, keepF, rk0, keptC0);
    k_rankkept<<<NWIN, 64, 0, stream>>>(cnt1, base1, seg1, keepF, rk1, keptC1);
    k_conti<<<1, 256, 0, stream>>>(lvlW0, keptC0, conti0);
    k_conti<<<1, 256, 0, stream>>>(lvlW1, keptC1, conti1);
    k_final<<<nb, 256, 0, stream>>>(n, w0a, w1a, keep0, keepF, lvlW0, lvlW1,
                                    conti0, conti1, rk0, rk1, out);
    int fb = (n * 32 + 255) / 256;
    k_feat<<<fb, 256, 0, stream>>>((const float4*)feat, keepF, (float4*)out, n);
}